// Round 4
// baseline (294.291 us; speedup 1.0000x reference)
//
#include <hip/hip_runtime.h>
#include <hip/hip_bf16.h>
#include <math.h>

#define Bn 8
#define Tn 2048
#define Cn 1024
#define Hn 64
#define BTHb ((size_t)Bn * Tn * Hn)   // elements per projected matrix (bf16)

typedef __attribute__((ext_vector_type(8))) short bf16x8;
typedef __attribute__((ext_vector_type(4))) float f32x4;

static __device__ __forceinline__ unsigned short bf16rne(float f) {
    union { float f; unsigned u; } x; x.f = f;
    return (unsigned short)((x.u + 0x7FFFu + ((x.u >> 16) & 1u)) >> 16);
}

// HW round-to-nearest-even f32->bf16 (pairs into v_cvt_pk_bf16_f32)
static __device__ __forceinline__ unsigned short hwbf16(float f) {
    union { __hip_bfloat16 h; unsigned short u; } c;
    c.h = __float2bfloat16(f);
    return c.u;
}

static __device__ __forceinline__ bf16x8 cvt8(const float4 a, const float4 b) {
    bf16x8 r;
    r[0] = (short)hwbf16(a.x); r[1] = (short)hwbf16(a.y);
    r[2] = (short)hwbf16(a.z); r[3] = (short)hwbf16(a.w);
    r[4] = (short)hwbf16(b.x); r[5] = (short)hwbf16(b.y);
    r[6] = (short)hwbf16(b.z); r[7] = (short)hwbf16(b.w);
    return r;
}

// ---------------------------------------------------------------------------
// MFMA projection -> bf16 output: O[row,h] = sum_c X[row,c] * W[h,c]
// v5: BARRIER-FREE main loop. Evidence from v1-v4: three different staging
// structures all cost ~84us = ~4200 cyc/phase while waves are ~12% busy --
// the 2-barriers-per-chunk lockstep exposes serial memory latency every
// chunk and no source-level pipelining survives it. Structural fix: each
// wave only ever consumes its OWN 16 X-rows; only W is shared. So W (256KB,
// L2-hot) is staged ONCE per block as pre-arranged bf16 MFMA B-fragments in
// LDS (128KB, unit u=(kc32*4+ht)*64+lane -> ds_read_b128 at base+lane*16,
// conflict-free), one __syncthreads, then each wave independently streams
// its X rows global->A-frags->MFMA with zero barriers: 64 independent
// global loads per wave give the scheduler a deep window, and waves drift
// freely so latency overlaps across 8 waves (2/SIMD).
// grid (128,3) = 384 blocks x 512 threads; 128 rows x 64 h per block.
// ---------------------------------------------------------------------------
__global__ __launch_bounds__(512, 2) void proj_kernel(
    const float* __restrict__ k, const float* __restrict__ q,
    const float* __restrict__ v,
    const float* __restrict__ Wk, const float* __restrict__ Wq,
    const float* __restrict__ Wv,
    unsigned short* __restrict__ ws)
{
    const int which = blockIdx.y;
    const float* X = (which == 0) ? k : (which == 1) ? q : v;
    const float* W = (which == 0) ? Wk : (which == 1) ? Wq : Wv;
    unsigned short* O = ws + (size_t)which * BTHb;

    // W as bf16 B-fragments: unit u = (kc32*4 + ht)*64 + lane, 16B each.
    // unit holds W[ht*16 + (lane&15)][kc32*32 + (lane>>4)*8 + 0..7]. 128 KB.
    __shared__ unsigned short WL[8192 * 8];

    const int tid  = threadIdx.x;
    const int wave = __builtin_amdgcn_readfirstlane(tid >> 6);
    const int lane = tid & 63;
    const int m    = lane & 15;
    const int quad = lane >> 4;
    const int row0 = blockIdx.x * 128;

    // ---- prologue: stage all of W (64x1024 fp32 -> bf16 frags) ----
#pragma unroll
    for (int i = 0; i < 16; ++i) {
        const int u    = tid + 512 * i;
        const int kc32 = u >> 8;
        const int ht   = (u >> 6) & 3;
        const int l    = u & 63;
        const float* wp =
            W + (size_t)(ht * 16 + (l & 15)) * Cn + kc32 * 32 + (l >> 4) * 8;
        const float4 a = *(const float4*)wp;
        const float4 b = *(const float4*)(wp + 4);
        *(bf16x8*)&WL[(size_t)u * 8] = cvt8(a, b);
    }
    __syncthreads();   // the ONLY barrier

    // ---- barrier-free K-loop: wave streams its own 16 rows ----
    const float* Xr = X + (size_t)(row0 + wave * 16 + m) * Cn;

    f32x4 acc[4];
#pragma unroll
    for (int t = 0; t < 4; ++t) acc[t] = (f32x4){0.f, 0.f, 0.f, 0.f};

#pragma unroll 8
    for (int c = 0; c < 32; ++c) {     // K in chunks of 32
        const float4 a0 = *(const float4*)(Xr + c * 32 + quad * 8);
        const float4 a1 = *(const float4*)(Xr + c * 32 + quad * 8 + 4);
        const bf16x8 a = cvt8(a0, a1);
#pragma unroll
        for (int ht = 0; ht < 4; ++ht) {
            const bf16x8 bfr =
                *(const bf16x8*)&WL[(size_t)((c * 4 + ht) * 64 + lane) * 8];
            acc[ht] = __builtin_amdgcn_mfma_f32_16x16x32_bf16(
                a, bfr, acc[ht], 0, 0, 0);
        }
    }

    // D layout: col=lane&15, row=quad*4+reg
#pragma unroll
    for (int ht = 0; ht < 4; ++ht)
#pragma unroll
        for (int r = 0; r < 4; ++r)
            O[(size_t)(row0 + wave * 16 + quad * 4 + r) * Hn + ht * 16 + m] =
                bf16rne(acc[ht][r]);
}

// ---------------------------------------------------------------------------
// MFMA flash attention. grid (32, 8); block 256 = 4 waves. (unchanged)
// ---------------------------------------------------------------------------
__global__ __launch_bounds__(256) void attn_kernel(
    const unsigned short* __restrict__ ws,
    const int* __restrict__ mask,
    float* __restrict__ out)
{
    const unsigned short* kh = ws;
    const unsigned short* qh = ws + BTHb;
    const unsigned short* vh = ws + 2 * BTHb;

    const int b   = blockIdx.y;
    const int qt  = blockIdx.x;
    const int tid = threadIdx.x;
    const int wave = __builtin_amdgcn_readfirstlane(tid >> 6);
    const int lane = tid & 63;
    const int ln   = lane & 15;
    const int quad = lane >> 4;

    __shared__ unsigned short Ks[64][72];   // [kpos][dim]
    __shared__ unsigned short Vt[64][72];   // [dim][kpos]
    __shared__ unsigned short Ps[64][72];   // [q-row local][kpos]
    __shared__ int Msk[64];

    const int wrb = qt * 64 + wave * 16;    // wave's first q-row

    // Q A-frags: A[m=ln][k=quad*8+j], 2 chunks of K=32
    bf16x8 qa[2];
#pragma unroll
    for (int kc = 0; kc < 2; ++kc)
        qa[kc] = *(const bf16x8*)(qh + ((size_t)b * Tn + wrb + ln) * Hn
                                     + kc * 32 + quad * 8);

    f32x4 oacc[4];
#pragma unroll
    for (int t = 0; t < 4; ++t) oacc[t] = (f32x4){0.f, 0.f, 0.f, 0.f};
    float mrow[4] = {-1e30f, -1e30f, -1e30f, -1e30f};
    float lrow[4] = {0.f, 0.f, 0.f, 0.f};

    // staging: K by (row=tid>>2, seg=tid&3)  [coalesced global, b128 LDS]
    //          V by (col=tid&63, seg=tid>>6) [conflict-free transpose writes]
    const int krow = tid >> 2, kseg = tid & 3;
    const int vcol = tid & 63, vseg = tid >> 6;

    uint4 kreg[2], vreg[2];
    int mreg = 0;
    {
        const unsigned short* kp =
            kh + ((size_t)b * Tn + krow) * Hn + kseg * 16;
        kreg[0] = *(const uint4*)kp;
        kreg[1] = *(const uint4*)(kp + 8);
        const unsigned short* vp =
            vh + ((size_t)b * Tn + vcol) * Hn + vseg * 16;
        vreg[0] = *(const uint4*)vp;
        vreg[1] = *(const uint4*)(vp + 8);
        if (tid < 64) mreg = mask[(size_t)b * Tn + tid];
    }

    for (int j = 0; j <= qt; ++j) {
        __syncthreads();   // previous tile's LDS readers done
        *(uint4*)&Ks[krow][kseg * 16]     = kreg[0];
        *(uint4*)&Ks[krow][kseg * 16 + 8] = kreg[1];
        {
            const unsigned short* vs = (const unsigned short*)vreg;
#pragma unroll
            for (int jj = 0; jj < 16; ++jj)
                Vt[vseg * 16 + jj][vcol] = vs[jj];
        }
        if (tid < 64) Msk[tid] = mreg;
        __syncthreads();   // staged tile visible

        if (j < qt) {      // prefetch next tile; latency overlaps compute
            const unsigned short* kp =
                kh + ((size_t)b * Tn + (j + 1) * 64 + krow) * Hn + kseg * 16;
            kreg[0] = *(const uint4*)kp;
            kreg[1] = *(const uint4*)(kp + 8);
            const unsigned short* vp =
                vh + ((size_t)b * Tn + (j + 1) * 64 + vcol) * Hn + vseg * 16;
            vreg[0] = *(const uint4*)vp;
            vreg[1] = *(const uint4*)(vp + 8);
            if (tid < 64) mreg = mask[(size_t)b * Tn + (j + 1) * 64 + tid];
        }

        // ---- S = Q K^T : 4 col-tiles (16 kpos each) x 2 K-chunks ----
        f32x4 sacc[4];
#pragma unroll
        for (int t = 0; t < 4; ++t) sacc[t] = (f32x4){0.f, 0.f, 0.f, 0.f};
#pragma unroll
        for (int kc = 0; kc < 2; ++kc) {
#pragma unroll
            for (int nt = 0; nt < 4; ++nt) {
                const bf16x8 kb =
                    *(const bf16x8*)&Ks[nt * 16 + ln][kc * 32 + quad * 8];
                sacc[nt] = __builtin_amdgcn_mfma_f32_16x16x32_bf16(
                    qa[kc], kb, sacc[nt], 0, 0, 0);
            }
        }

        // ---- online softmax in C-layout (rows quad*4+r, col nt*16+ln) ----
        const bool fullv = (j < qt);   // tile fully causal-valid for block
        float pv[4][4];
        float mt[4] = {-1e30f, -1e30f, -1e30f, -1e30f};
#pragma unroll
        for (int nt = 0; nt < 4; ++nt) {
            const bool mk = (Msk[nt * 16 + ln] != 0);
            const int kpos = j * 64 + nt * 16 + ln;
#pragma unroll
            for (int r = 0; r < 4; ++r) {
                float s = sacc[nt][r] * 0.125f;
                const bool valid =
                    mk && (fullv || kpos <= wrb + quad * 4 + r);
                s = valid ? s : -1e30f;
                pv[nt][r] = s;
                mt[r] = fmaxf(mt[r], s);
            }
        }
#pragma unroll
        for (int r = 0; r < 4; ++r) {
            mt[r] = fmaxf(mt[r], __shfl_xor(mt[r], 1));
            mt[r] = fmaxf(mt[r], __shfl_xor(mt[r], 2));
            mt[r] = fmaxf(mt[r], __shfl_xor(mt[r], 4));
            mt[r] = fmaxf(mt[r], __shfl_xor(mt[r], 8));
        }
        float alpha[4], rsum[4];
#pragma unroll
        for (int r = 0; r < 4; ++r) {
            const float mn = fmaxf(mrow[r], mt[r]);
            alpha[r] = __expf(mrow[r] - mn);
            mrow[r] = mn;
            rsum[r] = 0.f;
        }
#pragma unroll
        for (int nt = 0; nt < 4; ++nt)
#pragma unroll
            for (int r = 0; r < 4; ++r) {
                const float p = (pv[nt][r] <= -1e29f)
                                    ? 0.f
                                    : __expf(pv[nt][r] - mrow[r]);
                pv[nt][r] = p;
                rsum[r] += p;
            }
#pragma unroll
        for (int r = 0; r < 4; ++r) {
            rsum[r] += __shfl_xor(rsum[r], 1);
            rsum[r] += __shfl_xor(rsum[r], 2);
            rsum[r] += __shfl_xor(rsum[r], 4);
            rsum[r] += __shfl_xor(rsum[r], 8);
            lrow[r] = lrow[r] * alpha[r] + rsum[r];
        }
#pragma unroll
        for (int nt = 0; nt < 4; ++nt)
#pragma unroll
            for (int r = 0; r < 4; ++r) oacc[nt][r] *= alpha[r];

        // ---- P -> LDS (bf16), wave-private region ----
#pragma unroll
        for (int nt = 0; nt < 4; ++nt)
#pragma unroll
            for (int r = 0; r < 4; ++r)
                Ps[wave * 16 + quad * 4 + r][nt * 16 + ln] =
                    bf16rne(pv[nt][r]);
        // wave-private LDS round-trip: drain DS writes, keep vmcnt in flight
        asm volatile("s_waitcnt lgkmcnt(0)" ::: "memory");

        // ---- O += P V : A=P[m=ln][k], B=V^T[n=dim][k] ----
#pragma unroll
        for (int kc = 0; kc < 2; ++kc) {
            const bf16x8 pa =
                *(const bf16x8*)&Ps[wave * 16 + ln][kc * 32 + quad * 8];
#pragma unroll
            for (int nt = 0; nt < 4; ++nt) {
                const bf16x8 vb =
                    *(const bf16x8*)&Vt[nt * 16 + ln][kc * 32 + quad * 8];
                oacc[nt] = __builtin_amdgcn_mfma_f32_16x16x32_bf16(
                    pa, vb, oacc[nt], 0, 0, 0);
            }
        }
    }

    // ---- epilogue: divide by l, fp32 store ----
#pragma unroll
    for (int r = 0; r < 4; ++r) {
        const float inv = 1.0f / lrow[r];
        const size_t rowoff = ((size_t)b * Tn + wrb + quad * 4 + r) * Hn;
#pragma unroll
        for (int nt = 0; nt < 4; ++nt)
            out[rowoff + nt * 16 + ln] = oacc[nt][r] * inv;
    }
}

extern "C" void kernel_launch(void* const* d_in, const int* in_sizes, int n_in,
                              void* d_out, int out_size, void* d_ws, size_t ws_size,
                              hipStream_t stream)
{
    const float* k    = (const float*)d_in[0];
    const float* q    = (const float*)d_in[1];
    const float* v    = (const float*)d_in[2];
    const int*   mask = (const int*)d_in[3];
    const float* Wk   = (const float*)d_in[4];
    const float* Wq   = (const float*)d_in[5];
    const float* Wv   = (const float*)d_in[6];
    float* out = (float*)d_out;
    unsigned short* ws = (unsigned short*)d_ws;  // kh|qh|vh bf16, 6.3 MB

    dim3 pb(512), pg(Bn * Tn / 128, 3);
    proj_kernel<<<pg, pb, 0, stream>>>(k, q, v, Wk, Wq, Wv, ws);

    dim3 ab(256), ag(Tn / 64, Bn);
    attn_kernel<<<ag, ab, 0, stream>>>(ws, mask, out);
}

// Round 5
// 286.578 us; speedup vs baseline: 1.0269x; 1.0269x over previous
//
#include <hip/hip_runtime.h>
#include <hip/hip_bf16.h>
#include <math.h>

#define Bn 8
#define Tn 2048
#define Cn 1024
#define Hn 64
#define BTHb ((size_t)Bn * Tn * Hn)   // elements per projected matrix (bf16)
#define WLU  8192                     // 16B W-fragment units per matrix
#define WLS  ((size_t)WLU * 8)        // shorts per matrix (128 KB)

typedef __attribute__((ext_vector_type(8))) short bf16x8;
typedef __attribute__((ext_vector_type(4))) float f32x4;

static __device__ __forceinline__ unsigned short bf16rne(float f) {
    union { float f; unsigned u; } x; x.f = f;
    return (unsigned short)((x.u + 0x7FFFu + ((x.u >> 16) & 1u)) >> 16);
}

// HW round-to-nearest-even f32->bf16 (pairs into v_cvt_pk_bf16_f32)
static __device__ __forceinline__ unsigned short hwbf16(float f) {
    union { __hip_bfloat16 h; unsigned short u; } c;
    c.h = __float2bfloat16(f);
    return c.u;
}

static __device__ __forceinline__ bf16x8 cvt8(const float4 a, const float4 b) {
    bf16x8 r;
    r[0] = (short)hwbf16(a.x); r[1] = (short)hwbf16(a.y);
    r[2] = (short)hwbf16(a.z); r[3] = (short)hwbf16(a.w);
    r[4] = (short)hwbf16(b.x); r[5] = (short)hwbf16(b.y);
    r[6] = (short)hwbf16(b.z); r[7] = (short)hwbf16(b.w);
    return r;
}

// ---------------------------------------------------------------------------
// W pre-conversion: fp32 W[h][c] -> bf16 MFMA B-fragments, fragment-ordered.
// unit u = (kc32*4 + ht)*64 + lane holds W[ht*16 + (lane&15)]
//                                        [kc32*32 + (lane>>4)*8 + 0..7].
// Output parked in d_out (4 MB; attn fully overwrites it afterwards).
// grid (8,3) x 256 threads -- ~1-2 us.
// ---------------------------------------------------------------------------
__global__ __launch_bounds__(256) void wconv_kernel(
    const float* __restrict__ Wk, const float* __restrict__ Wq,
    const float* __restrict__ Wv, unsigned short* __restrict__ WL)
{
    const int which = blockIdx.y;
    const float* W = (which == 0) ? Wk : (which == 1) ? Wq : Wv;
    unsigned short* dst = WL + (size_t)which * WLS;
    const int tid = threadIdx.x;
#pragma unroll
    for (int i = 0; i < 4; ++i) {
        const int u    = blockIdx.x * 1024 + i * 256 + tid;
        const int kc32 = u >> 8;
        const int ht   = (u >> 6) & 3;
        const int l    = u & 63;
        const float* wp =
            W + (size_t)(ht * 16 + (l & 15)) * Cn + kc32 * 32 + (l >> 4) * 8;
        const float4 a = *(const float4*)wp;
        const float4 b = *(const float4*)(wp + 4);
        *(bf16x8*)&dst[(size_t)u * 8] = cvt8(a, b);
    }
}

// ---------------------------------------------------------------------------
// MFMA projection -> bf16 output: O[row,h] = sum_c X[row,c] * W[h,c]
// v6: NO LDS, NO barriers. v5 proved the barrier-free concept but crippled
// it with 128KB LDS (1 block/CU, 1.5 grid rounds) + per-block W prologue.
// Now W fragments come pre-converted from wconv's WL (L2-resident, 384 KB
// per XCD): each MFMA B-operand is a contiguous 1KB wave load that hits L2.
// Each of the 12 independent waves/CU streams its own 16 X-rows ->
// cvt -> MFMA with no synchronization anywhere, so memory latency overlaps
// across waves instead of being exposed per-chunk by barrier lockstep
// (v1-v4: ~1.3 TB/s). grid (256,3) x 256 thr; launch_bounds(256,3) gives
// the allocator ~168 VGPRs to hold the unroll-4 load window.
// ---------------------------------------------------------------------------
__global__ __launch_bounds__(256, 3) void proj_kernel(
    const float* __restrict__ k, const float* __restrict__ q,
    const float* __restrict__ v,
    const unsigned short* __restrict__ WL,
    unsigned short* __restrict__ ws)
{
    const int which = blockIdx.y;
    const float* X = (which == 0) ? k : (which == 1) ? q : v;
    const unsigned short* WLm = WL + (size_t)which * WLS;
    unsigned short* O = ws + (size_t)which * BTHb;

    const int tid  = threadIdx.x;
    const int wave = __builtin_amdgcn_readfirstlane(tid >> 6);
    const int lane = tid & 63;
    const int m    = lane & 15;
    const int quad = lane >> 4;
    const int row0 = blockIdx.x * 64;

    const float* Xr = X + (size_t)(row0 + wave * 16 + m) * Cn;

    f32x4 acc[4];
#pragma unroll
    for (int t = 0; t < 4; ++t) acc[t] = (f32x4){0.f, 0.f, 0.f, 0.f};

#pragma unroll 4
    for (int c = 0; c < 32; ++c) {     // K in chunks of 32
        const float4 a0 = *(const float4*)(Xr + c * 32 + quad * 8);
        const float4 a1 = *(const float4*)(Xr + c * 32 + quad * 8 + 4);
        const bf16x8 a = cvt8(a0, a1);
#pragma unroll
        for (int ht = 0; ht < 4; ++ht) {
            const bf16x8 bfr =
                *(const bf16x8*)&WLm[(size_t)((c * 4 + ht) * 64 + lane) * 8];
            acc[ht] = __builtin_amdgcn_mfma_f32_16x16x32_bf16(
                a, bfr, acc[ht], 0, 0, 0);
        }
    }

    // D layout: col=lane&15, row=quad*4+reg
#pragma unroll
    for (int ht = 0; ht < 4; ++ht)
#pragma unroll
        for (int r = 0; r < 4; ++r)
            O[(size_t)(row0 + wave * 16 + quad * 4 + r) * Hn + ht * 16 + m] =
                bf16rne(acc[ht][r]);
}

// ---------------------------------------------------------------------------
// MFMA flash attention. grid (32, 8); block 256 = 4 waves. (unchanged)
// ---------------------------------------------------------------------------
__global__ __launch_bounds__(256) void attn_kernel(
    const unsigned short* __restrict__ ws,
    const int* __restrict__ mask,
    float* __restrict__ out)
{
    const unsigned short* kh = ws;
    const unsigned short* qh = ws + BTHb;
    const unsigned short* vh = ws + 2 * BTHb;

    const int b   = blockIdx.y;
    const int qt  = blockIdx.x;
    const int tid = threadIdx.x;
    const int wave = __builtin_amdgcn_readfirstlane(tid >> 6);
    const int lane = tid & 63;
    const int ln   = lane & 15;
    const int quad = lane >> 4;

    __shared__ unsigned short Ks[64][72];   // [kpos][dim]
    __shared__ unsigned short Vt[64][72];   // [dim][kpos]
    __shared__ unsigned short Ps[64][72];   // [q-row local][kpos]
    __shared__ int Msk[64];

    const int wrb = qt * 64 + wave * 16;    // wave's first q-row

    // Q A-frags: A[m=ln][k=quad*8+j], 2 chunks of K=32
    bf16x8 qa[2];
#pragma unroll
    for (int kc = 0; kc < 2; ++kc)
        qa[kc] = *(const bf16x8*)(qh + ((size_t)b * Tn + wrb + ln) * Hn
                                     + kc * 32 + quad * 8);

    f32x4 oacc[4];
#pragma unroll
    for (int t = 0; t < 4; ++t) oacc[t] = (f32x4){0.f, 0.f, 0.f, 0.f};
    float mrow[4] = {-1e30f, -1e30f, -1e30f, -1e30f};
    float lrow[4] = {0.f, 0.f, 0.f, 0.f};

    // staging: K by (row=tid>>2, seg=tid&3)  [coalesced global, b128 LDS]
    //          V by (col=tid&63, seg=tid>>6) [conflict-free transpose writes]
    const int krow = tid >> 2, kseg = tid & 3;
    const int vcol = tid & 63, vseg = tid >> 6;

    uint4 kreg[2], vreg[2];
    int mreg = 0;
    {
        const unsigned short* kp =
            kh + ((size_t)b * Tn + krow) * Hn + kseg * 16;
        kreg[0] = *(const uint4*)kp;
        kreg[1] = *(const uint4*)(kp + 8);
        const unsigned short* vp =
            vh + ((size_t)b * Tn + vcol) * Hn + vseg * 16;
        vreg[0] = *(const uint4*)vp;
        vreg[1] = *(const uint4*)(vp + 8);
        if (tid < 64) mreg = mask[(size_t)b * Tn + tid];
    }

    for (int j = 0; j <= qt; ++j) {
        __syncthreads();   // previous tile's LDS readers done
        *(uint4*)&Ks[krow][kseg * 16]     = kreg[0];
        *(uint4*)&Ks[krow][kseg * 16 + 8] = kreg[1];
        {
            const unsigned short* vs = (const unsigned short*)vreg;
#pragma unroll
            for (int jj = 0; jj < 16; ++jj)
                Vt[vseg * 16 + jj][vcol] = vs[jj];
        }
        if (tid < 64) Msk[tid] = mreg;
        __syncthreads();   // staged tile visible

        if (j < qt) {      // prefetch next tile; latency overlaps compute
            const unsigned short* kp =
                kh + ((size_t)b * Tn + (j + 1) * 64 + krow) * Hn + kseg * 16;
            kreg[0] = *(const uint4*)kp;
            kreg[1] = *(const uint4*)(kp + 8);
            const unsigned short* vp =
                vh + ((size_t)b * Tn + (j + 1) * 64 + vcol) * Hn + vseg * 16;
            vreg[0] = *(const uint4*)vp;
            vreg[1] = *(const uint4*)(vp + 8);
            if (tid < 64) mreg = mask[(size_t)b * Tn + (j + 1) * 64 + tid];
        }

        // ---- S = Q K^T : 4 col-tiles (16 kpos each) x 2 K-chunks ----
        f32x4 sacc[4];
#pragma unroll
        for (int t = 0; t < 4; ++t) sacc[t] = (f32x4){0.f, 0.f, 0.f, 0.f};
#pragma unroll
        for (int kc = 0; kc < 2; ++kc) {
#pragma unroll
            for (int nt = 0; nt < 4; ++nt) {
                const bf16x8 kb =
                    *(const bf16x8*)&Ks[nt * 16 + ln][kc * 32 + quad * 8];
                sacc[nt] = __builtin_amdgcn_mfma_f32_16x16x32_bf16(
                    qa[kc], kb, sacc[nt], 0, 0, 0);
            }
        }

        // ---- online softmax in C-layout (rows quad*4+r, col nt*16+ln) ----
        const bool fullv = (j < qt);   // tile fully causal-valid for block
        float pv[4][4];
        float mt[4] = {-1e30f, -1e30f, -1e30f, -1e30f};
#pragma unroll
        for (int nt = 0; nt < 4; ++nt) {
            const bool mk = (Msk[nt * 16 + ln] != 0);
            const int kpos = j * 64 + nt * 16 + ln;
#pragma unroll
            for (int r = 0; r < 4; ++r) {
                float s = sacc[nt][r] * 0.125f;
                const bool valid =
                    mk && (fullv || kpos <= wrb + quad * 4 + r);
                s = valid ? s : -1e30f;
                pv[nt][r] = s;
                mt[r] = fmaxf(mt[r], s);
            }
        }
#pragma unroll
        for (int r = 0; r < 4; ++r) {
            mt[r] = fmaxf(mt[r], __shfl_xor(mt[r], 1));
            mt[r] = fmaxf(mt[r], __shfl_xor(mt[r], 2));
            mt[r] = fmaxf(mt[r], __shfl_xor(mt[r], 4));
            mt[r] = fmaxf(mt[r], __shfl_xor(mt[r], 8));
        }
        float alpha[4], rsum[4];
#pragma unroll
        for (int r = 0; r < 4; ++r) {
            const float mn = fmaxf(mrow[r], mt[r]);
            alpha[r] = __expf(mrow[r] - mn);
            mrow[r] = mn;
            rsum[r] = 0.f;
        }
#pragma unroll
        for (int nt = 0; nt < 4; ++nt)
#pragma unroll
            for (int r = 0; r < 4; ++r) {
                const float p = (pv[nt][r] <= -1e29f)
                                    ? 0.f
                                    : __expf(pv[nt][r] - mrow[r]);
                pv[nt][r] = p;
                rsum[r] += p;
            }
#pragma unroll
        for (int r = 0; r < 4; ++r) {
            rsum[r] += __shfl_xor(rsum[r], 1);
            rsum[r] += __shfl_xor(rsum[r], 2);
            rsum[r] += __shfl_xor(rsum[r], 4);
            rsum[r] += __shfl_xor(rsum[r], 8);
            lrow[r] = lrow[r] * alpha[r] + rsum[r];
        }
#pragma unroll
        for (int nt = 0; nt < 4; ++nt)
#pragma unroll
            for (int r = 0; r < 4; ++r) oacc[nt][r] *= alpha[r];

        // ---- P -> LDS (bf16), wave-private region ----
#pragma unroll
        for (int nt = 0; nt < 4; ++nt)
#pragma unroll
            for (int r = 0; r < 4; ++r)
                Ps[wave * 16 + quad * 4 + r][nt * 16 + ln] =
                    bf16rne(pv[nt][r]);
        // wave-private LDS round-trip: drain DS writes, keep vmcnt in flight
        asm volatile("s_waitcnt lgkmcnt(0)" ::: "memory");

        // ---- O += P V : A=P[m=ln][k], B=V^T[n=dim][k] ----
#pragma unroll
        for (int kc = 0; kc < 2; ++kc) {
            const bf16x8 pa =
                *(const bf16x8*)&Ps[wave * 16 + ln][kc * 32 + quad * 8];
#pragma unroll
            for (int nt = 0; nt < 4; ++nt) {
                const bf16x8 vb =
                    *(const bf16x8*)&Vt[nt * 16 + ln][kc * 32 + quad * 8];
                oacc[nt] = __builtin_amdgcn_mfma_f32_16x16x32_bf16(
                    pa, vb, oacc[nt], 0, 0, 0);
            }
        }
    }

    // ---- epilogue: divide by l, fp32 store ----
#pragma unroll
    for (int r = 0; r < 4; ++r) {
        const float inv = 1.0f / lrow[r];
        const size_t rowoff = ((size_t)b * Tn + wrb + quad * 4 + r) * Hn;
#pragma unroll
        for (int nt = 0; nt < 4; ++nt)
            out[rowoff + nt * 16 + ln] = oacc[nt][r] * inv;
    }
}

extern "C" void kernel_launch(void* const* d_in, const int* in_sizes, int n_in,
                              void* d_out, int out_size, void* d_ws, size_t ws_size,
                              hipStream_t stream)
{
    const float* k    = (const float*)d_in[0];
    const float* q    = (const float*)d_in[1];
    const float* v    = (const float*)d_in[2];
    const int*   mask = (const int*)d_in[3];
    const float* Wk   = (const float*)d_in[4];
    const float* Wq   = (const float*)d_in[5];
    const float* Wv   = (const float*)d_in[6];
    float* out = (float*)d_out;
    unsigned short* ws = (unsigned short*)d_ws;  // kh|qh|vh bf16, 6.3 MB

    // WL scratch lives in d_out (384 KB of 4 MB); attn fully overwrites out.
    unsigned short* WL = (unsigned short*)d_out;

    dim3 wb(256), wg(8, 3);
    wconv_kernel<<<wg, wb, 0, stream>>>(Wk, Wq, Wv, WL);

    dim3 pb(256), pg(Bn * Tn / 64, 3);
    proj_kernel<<<pg, pb, 0, stream>>>(k, q, v, WL, ws);

    dim3 ab(256), ag(Tn / 64, Bn);
    attn_kernel<<<ag, ab, 0, stream>>>(ws, mask, out);
}

// Round 6
// 281.934 us; speedup vs baseline: 1.0438x; 1.0165x over previous
//
#include <hip/hip_runtime.h>
#include <hip/hip_bf16.h>
#include <math.h>

#define Bn 8
#define Tn 2048
#define Cn 1024
#define Hn 64
#define BTHb ((size_t)Bn * Tn * Hn)   // elements per projected matrix (bf16)
#define WLU  8192                     // 16B W-fragment units per matrix
#define WLS  ((size_t)WLU * 8)        // shorts per matrix (128 KB)

typedef __attribute__((ext_vector_type(8))) short bf16x8;
typedef __attribute__((ext_vector_type(4))) float f32x4;

static __device__ __forceinline__ unsigned short bf16rne(float f) {
    union { float f; unsigned u; } x; x.f = f;
    return (unsigned short)((x.u + 0x7FFFu + ((x.u >> 16) & 1u)) >> 16);
}

// HW round-to-nearest-even f32->bf16 (pairs into v_cvt_pk_bf16_f32)
static __device__ __forceinline__ unsigned short hwbf16(float f) {
    union { __hip_bfloat16 h; unsigned short u; } c;
    c.h = __float2bfloat16(f);
    return c.u;
}

static __device__ __forceinline__ bf16x8 cvt8(const float4 a, const float4 b) {
    bf16x8 r;
    r[0] = (short)hwbf16(a.x); r[1] = (short)hwbf16(a.y);
    r[2] = (short)hwbf16(a.z); r[3] = (short)hwbf16(a.w);
    r[4] = (short)hwbf16(b.x); r[5] = (short)hwbf16(b.y);
    r[6] = (short)hwbf16(b.z); r[7] = (short)hwbf16(b.w);
    return r;
}

// ---------------------------------------------------------------------------
// W pre-conversion: fp32 W[h][c] -> bf16 MFMA B-fragments, fragment-ordered.
// unit u = (kc32*4 + ht)*64 + lane holds W[ht*16 + (lane&15)]
//                                        [kc32*32 + (lane>>4)*8 + 0..7].
// Output parked in d_out (384 KB of 4 MB; attn fully overwrites out after).
// ---------------------------------------------------------------------------
__global__ __launch_bounds__(256) void wconv_kernel(
    const float* __restrict__ Wk, const float* __restrict__ Wq,
    const float* __restrict__ Wv, unsigned short* __restrict__ WL)
{
    const int which = blockIdx.y;
    const float* W = (which == 0) ? Wk : (which == 1) ? Wq : Wv;
    unsigned short* dst = WL + (size_t)which * WLS;
    const int tid = threadIdx.x;
#pragma unroll
    for (int i = 0; i < 4; ++i) {
        const int u    = blockIdx.x * 1024 + i * 256 + tid;
        const int kc32 = u >> 8;
        const int ht   = (u >> 6) & 3;
        const int l    = u & 63;
        const float* wp =
            W + (size_t)(ht * 16 + (l & 15)) * Cn + kc32 * 32 + (l >> 4) * 8;
        const float4 a = *(const float4*)wp;
        const float4 b = *(const float4*)(wp + 4);
        *(bf16x8*)&dst[(size_t)u * 8] = cvt8(a, b);
    }
}

// ---------------------------------------------------------------------------
// MFMA projection -> bf16 output: O[row,h] = sum_c X[row,c] * W[h,c]
// v7: K-SPLIT x4 for occupancy. v1-v6 (six structures: lockstep LDS,
// reg-prefetch x2, global_load_lds+counted-vmcnt, barrier-free) all sit at
// ~85us / ~1.3 TB/s with VALUBusy <10%: latency-bound, and the compiler
// never keeps >~1 load in flight per wave. The only untouched knob is wave
// count: 16-rows-per-wave fixed it at 12 waves/CU. Now each block's 4
// waves share the SAME 16 rows, each wave owns a K-quarter (8 chunks of
// 32); partial accs combine through 13KB LDS (stride-17, conflict-free)
// with one barrier; wave 0 writes. Grid (1024,3) -> 8 resident blocks/CU
// = 32 waves/CU (2.7x). launch_bounds(256,8) caps VGPR at 64 so full
// occupancy is real (v6 needed only 28).
// ---------------------------------------------------------------------------
__global__ __launch_bounds__(256, 8) void proj_kernel(
    const float* __restrict__ k, const float* __restrict__ q,
    const float* __restrict__ v,
    const unsigned short* __restrict__ WL,
    unsigned short* __restrict__ ws)
{
    const int which = blockIdx.y;
    const float* X = (which == 0) ? k : (which == 1) ? q : v;
    const unsigned short* WLm = WL + (size_t)which * WLS;
    unsigned short* O = ws + (size_t)which * BTHb;

    const int tid  = threadIdx.x;
    const int wave = __builtin_amdgcn_readfirstlane(tid >> 6);  // K-quarter
    const int lane = tid & 63;
    const int m    = lane & 15;
    const int quad = lane >> 4;
    const int row0 = blockIdx.x * 16;

    const float* Xr = X + (size_t)(row0 + m) * Cn;

    f32x4 acc[4];
#pragma unroll
    for (int t = 0; t < 4; ++t) acc[t] = (f32x4){0.f, 0.f, 0.f, 0.f};

#pragma unroll
    for (int cc = 0; cc < 8; ++cc) {   // wave's 8 K-chunks of 32
        const int c = wave * 8 + cc;
        const float4 a0 = *(const float4*)(Xr + c * 32 + quad * 8);
        const float4 a1 = *(const float4*)(Xr + c * 32 + quad * 8 + 4);
        const bf16x8 a = cvt8(a0, a1);
#pragma unroll
        for (int ht = 0; ht < 4; ++ht) {
            const bf16x8 bfr =
                *(const bf16x8*)&WLm[(size_t)((c * 4 + ht) * 64 + lane) * 8];
            acc[ht] = __builtin_amdgcn_mfma_f32_16x16x32_bf16(
                a, bfr, acc[ht], 0, 0, 0);
        }
    }

    // ---- cross-wave K-reduction via LDS (stride 17 -> conflict-free) ----
    __shared__ float Rs[3][64][17];
    if (wave > 0) {
#pragma unroll
        for (int ht = 0; ht < 4; ++ht)
#pragma unroll
            for (int r = 0; r < 4; ++r)
                Rs[wave - 1][lane][ht * 4 + r] = acc[ht][r];
    }
    __syncthreads();
    if (wave == 0) {
#pragma unroll
        for (int w = 0; w < 3; ++w)
#pragma unroll
            for (int ht = 0; ht < 4; ++ht)
#pragma unroll
                for (int r = 0; r < 4; ++r)
                    acc[ht][r] += Rs[w][lane][ht * 4 + r];

        // D layout: col=lane&15, row=quad*4+reg
#pragma unroll
        for (int ht = 0; ht < 4; ++ht)
#pragma unroll
            for (int r = 0; r < 4; ++r)
                O[(size_t)(row0 + quad * 4 + r) * Hn + ht * 16 + m] =
                    bf16rne(acc[ht][r]);
    }
}

// ---------------------------------------------------------------------------
// MFMA flash attention. grid (32, 8); block 256 = 4 waves. (unchanged)
// ---------------------------------------------------------------------------
__global__ __launch_bounds__(256) void attn_kernel(
    const unsigned short* __restrict__ ws,
    const int* __restrict__ mask,
    float* __restrict__ out)
{
    const unsigned short* kh = ws;
    const unsigned short* qh = ws + BTHb;
    const unsigned short* vh = ws + 2 * BTHb;

    const int b   = blockIdx.y;
    const int qt  = blockIdx.x;
    const int tid = threadIdx.x;
    const int wave = __builtin_amdgcn_readfirstlane(tid >> 6);
    const int lane = tid & 63;
    const int ln   = lane & 15;
    const int quad = lane >> 4;

    __shared__ unsigned short Ks[64][72];   // [kpos][dim]
    __shared__ unsigned short Vt[64][72];   // [dim][kpos]
    __shared__ unsigned short Ps[64][72];   // [q-row local][kpos]
    __shared__ int Msk[64];

    const int wrb = qt * 64 + wave * 16;    // wave's first q-row

    // Q A-frags: A[m=ln][k=quad*8+j], 2 chunks of K=32
    bf16x8 qa[2];
#pragma unroll
    for (int kc = 0; kc < 2; ++kc)
        qa[kc] = *(const bf16x8*)(qh + ((size_t)b * Tn + wrb + ln) * Hn
                                     + kc * 32 + quad * 8);

    f32x4 oacc[4];
#pragma unroll
    for (int t = 0; t < 4; ++t) oacc[t] = (f32x4){0.f, 0.f, 0.f, 0.f};
    float mrow[4] = {-1e30f, -1e30f, -1e30f, -1e30f};
    float lrow[4] = {0.f, 0.f, 0.f, 0.f};

    // staging: K by (row=tid>>2, seg=tid&3)  [coalesced global, b128 LDS]
    //          V by (col=tid&63, seg=tid>>6) [conflict-free transpose writes]
    const int krow = tid >> 2, kseg = tid & 3;
    const int vcol = tid & 63, vseg = tid >> 6;

    uint4 kreg[2], vreg[2];
    int mreg = 0;
    {
        const unsigned short* kp =
            kh + ((size_t)b * Tn + krow) * Hn + kseg * 16;
        kreg[0] = *(const uint4*)kp;
        kreg[1] = *(const uint4*)(kp + 8);
        const unsigned short* vp =
            vh + ((size_t)b * Tn + vcol) * Hn + vseg * 16;
        vreg[0] = *(const uint4*)vp;
        vreg[1] = *(const uint4*)(vp + 8);
        if (tid < 64) mreg = mask[(size_t)b * Tn + tid];
    }

    for (int j = 0; j <= qt; ++j) {
        __syncthreads();   // previous tile's LDS readers done
        *(uint4*)&Ks[krow][kseg * 16]     = kreg[0];
        *(uint4*)&Ks[krow][kseg * 16 + 8] = kreg[1];
        {
            const unsigned short* vs = (const unsigned short*)vreg;
#pragma unroll
            for (int jj = 0; jj < 16; ++jj)
                Vt[vseg * 16 + jj][vcol] = vs[jj];
        }
        if (tid < 64) Msk[tid] = mreg;
        __syncthreads();   // staged tile visible

        if (j < qt) {      // prefetch next tile; latency overlaps compute
            const unsigned short* kp =
                kh + ((size_t)b * Tn + (j + 1) * 64 + krow) * Hn + kseg * 16;
            kreg[0] = *(const uint4*)kp;
            kreg[1] = *(const uint4*)(kp + 8);
            const unsigned short* vp =
                vh + ((size_t)b * Tn + (j + 1) * 64 + vcol) * Hn + vseg * 16;
            vreg[0] = *(const uint4*)vp;
            vreg[1] = *(const uint4*)(vp + 8);
            if (tid < 64) mreg = mask[(size_t)b * Tn + (j + 1) * 64 + tid];
        }

        // ---- S = Q K^T : 4 col-tiles (16 kpos each) x 2 K-chunks ----
        f32x4 sacc[4];
#pragma unroll
        for (int t = 0; t < 4; ++t) sacc[t] = (f32x4){0.f, 0.f, 0.f, 0.f};
#pragma unroll
        for (int kc = 0; kc < 2; ++kc) {
#pragma unroll
            for (int nt = 0; nt < 4; ++nt) {
                const bf16x8 kb =
                    *(const bf16x8*)&Ks[nt * 16 + ln][kc * 32 + quad * 8];
                sacc[nt] = __builtin_amdgcn_mfma_f32_16x16x32_bf16(
                    qa[kc], kb, sacc[nt], 0, 0, 0);
            }
        }

        // ---- online softmax in C-layout (rows quad*4+r, col nt*16+ln) ----
        const bool fullv = (j < qt);   // tile fully causal-valid for block
        float pv[4][4];
        float mt[4] = {-1e30f, -1e30f, -1e30f, -1e30f};
#pragma unroll
        for (int nt = 0; nt < 4; ++nt) {
            const bool mk = (Msk[nt * 16 + ln] != 0);
            const int kpos = j * 64 + nt * 16 + ln;
#pragma unroll
            for (int r = 0; r < 4; ++r) {
                float s = sacc[nt][r] * 0.125f;
                const bool valid =
                    mk && (fullv || kpos <= wrb + quad * 4 + r);
                s = valid ? s : -1e30f;
                pv[nt][r] = s;
                mt[r] = fmaxf(mt[r], s);
            }
        }
#pragma unroll
        for (int r = 0; r < 4; ++r) {
            mt[r] = fmaxf(mt[r], __shfl_xor(mt[r], 1));
            mt[r] = fmaxf(mt[r], __shfl_xor(mt[r], 2));
            mt[r] = fmaxf(mt[r], __shfl_xor(mt[r], 4));
            mt[r] = fmaxf(mt[r], __shfl_xor(mt[r], 8));
        }
        float alpha[4], rsum[4];
#pragma unroll
        for (int r = 0; r < 4; ++r) {
            const float mn = fmaxf(mrow[r], mt[r]);
            alpha[r] = __expf(mrow[r] - mn);
            mrow[r] = mn;
            rsum[r] = 0.f;
        }
#pragma unroll
        for (int nt = 0; nt < 4; ++nt)
#pragma unroll
            for (int r = 0; r < 4; ++r) {
                const float p = (pv[nt][r] <= -1e29f)
                                    ? 0.f
                                    : __expf(pv[nt][r] - mrow[r]);
                pv[nt][r] = p;
                rsum[r] += p;
            }
#pragma unroll
        for (int r = 0; r < 4; ++r) {
            rsum[r] += __shfl_xor(rsum[r], 1);
            rsum[r] += __shfl_xor(rsum[r], 2);
            rsum[r] += __shfl_xor(rsum[r], 4);
            rsum[r] += __shfl_xor(rsum[r], 8);
            lrow[r] = lrow[r] * alpha[r] + rsum[r];
        }
#pragma unroll
        for (int nt = 0; nt < 4; ++nt)
#pragma unroll
            for (int r = 0; r < 4; ++r) oacc[nt][r] *= alpha[r];

        // ---- P -> LDS (bf16), wave-private region ----
#pragma unroll
        for (int nt = 0; nt < 4; ++nt)
#pragma unroll
            for (int r = 0; r < 4; ++r)
                Ps[wave * 16 + quad * 4 + r][nt * 16 + ln] =
                    bf16rne(pv[nt][r]);
        // wave-private LDS round-trip: drain DS writes, keep vmcnt in flight
        asm volatile("s_waitcnt lgkmcnt(0)" ::: "memory");

        // ---- O += P V : A=P[m=ln][k], B=V^T[n=dim][k] ----
#pragma unroll
        for (int kc = 0; kc < 2; ++kc) {
            const bf16x8 pa =
                *(const bf16x8*)&Ps[wave * 16 + ln][kc * 32 + quad * 8];
#pragma unroll
            for (int nt = 0; nt < 4; ++nt) {
                const bf16x8 vb =
                    *(const bf16x8*)&Vt[nt * 16 + ln][kc * 32 + quad * 8];
                oacc[nt] = __builtin_amdgcn_mfma_f32_16x16x32_bf16(
                    pa, vb, oacc[nt], 0, 0, 0);
            }
        }
    }

    // ---- epilogue: divide by l, fp32 store ----
#pragma unroll
    for (int r = 0; r < 4; ++r) {
        const float inv = 1.0f / lrow[r];
        const size_t rowoff = ((size_t)b * Tn + wrb + quad * 4 + r) * Hn;
#pragma unroll
        for (int nt = 0; nt < 4; ++nt)
            out[rowoff + nt * 16 + ln] = oacc[nt][r] * inv;
    }
}

extern "C" void kernel_launch(void* const* d_in, const int* in_sizes, int n_in,
                              void* d_out, int out_size, void* d_ws, size_t ws_size,
                              hipStream_t stream)
{
    const float* k    = (const float*)d_in[0];
    const float* q    = (const float*)d_in[1];
    const float* v    = (const float*)d_in[2];
    const int*   mask = (const int*)d_in[3];
    const float* Wk   = (const float*)d_in[4];
    const float* Wq   = (const float*)d_in[5];
    const float* Wv   = (const float*)d_in[6];
    float* out = (float*)d_out;
    unsigned short* ws = (unsigned short*)d_ws;  // kh|qh|vh bf16, 6.3 MB

    // WL scratch lives in d_out (384 KB of 4 MB); attn fully overwrites out.
    unsigned short* WL = (unsigned short*)d_out;

    dim3 wb(256), wg(8, 3);
    wconv_kernel<<<wg, wb, 0, stream>>>(Wk, Wq, Wv, WL);

    dim3 pb(256), pg(Bn * Tn / 16, 3);
    proj_kernel<<<pg, pb, 0, stream>>>(k, q, v, WL, ws);

    dim3 ab(256), ag(Tn / 64, Bn);
    attn_kernel<<<ag, ab, 0, stream>>>(ws, mask, out);
}

// Round 7
// 278.390 us; speedup vs baseline: 1.0571x; 1.0127x over previous
//
#include <hip/hip_runtime.h>
#include <hip/hip_bf16.h>
#include <math.h>

#define Bn 8
#define Tn 2048
#define Cn 1024
#define Hn 64
#define BTHb ((size_t)Bn * Tn * Hn)   // elements per projected matrix (bf16)
#define WLU  8192                     // 16B W-fragment units per matrix
#define WLS  ((size_t)WLU * 8)        // shorts per matrix (128 KB)

typedef __attribute__((ext_vector_type(8))) short bf16x8;
typedef __attribute__((ext_vector_type(4))) float f32x4;

static __device__ __forceinline__ unsigned short bf16rne(float f) {
    union { float f; unsigned u; } x; x.f = f;
    return (unsigned short)((x.u + 0x7FFFu + ((x.u >> 16) & 1u)) >> 16);
}

// HW round-to-nearest-even f32->bf16 (pairs into v_cvt_pk_bf16_f32)
static __device__ __forceinline__ unsigned short hwbf16(float f) {
    union { __hip_bfloat16 h; unsigned short u; } c;
    c.h = __float2bfloat16(f);
    return c.u;
}

static __device__ __forceinline__ bf16x8 cvt8(const float4 a, const float4 b) {
    bf16x8 r;
    r[0] = (short)hwbf16(a.x); r[1] = (short)hwbf16(a.y);
    r[2] = (short)hwbf16(a.z); r[3] = (short)hwbf16(a.w);
    r[4] = (short)hwbf16(b.x); r[5] = (short)hwbf16(b.y);
    r[6] = (short)hwbf16(b.z); r[7] = (short)hwbf16(b.w);
    return r;
}

// ---------------------------------------------------------------------------
// W pre-conversion: fp32 W[h][c] -> bf16 MFMA B-fragments, fragment-ordered.
// unit u = (kc32*4 + ht)*64 + lane holds W[ht*16 + (lane&15)]
//                                        [kc32*32 + (lane>>4)*8 + 0..7].
// Output parked in d_out (384 KB of 4 MB; attn fully overwrites out after).
// ---------------------------------------------------------------------------
__global__ __launch_bounds__(256) void wconv_kernel(
    const float* __restrict__ Wk, const float* __restrict__ Wq,
    const float* __restrict__ Wv, unsigned short* __restrict__ WL)
{
    const int which = blockIdx.y;
    const float* W = (which == 0) ? Wk : (which == 1) ? Wq : Wv;
    unsigned short* dst = WL + (size_t)which * WLS;
    const int tid = threadIdx.x;
#pragma unroll
    for (int i = 0; i < 4; ++i) {
        const int u    = blockIdx.x * 1024 + i * 256 + tid;
        const int kc32 = u >> 8;
        const int ht   = (u >> 6) & 3;
        const int l    = u & 63;
        const float* wp =
            W + (size_t)(ht * 16 + (l & 15)) * Cn + kc32 * 32 + (l >> 4) * 8;
        const float4 a = *(const float4*)wp;
        const float4 b = *(const float4*)(wp + 4);
        *(bf16x8*)&dst[(size_t)u * 8] = cvt8(a, b);
    }
}

// ---------------------------------------------------------------------------
// MFMA projection -> bf16 output: O[row,h] = sum_c X[row,c] * W[h,c]
// v8: SEQUENTIAL global reads. v1-v7 varied barriers / staging mechanism /
// prefetch depth / occupancy (12->26 waves/CU) and BW never moved off
// ~1.3 TB/s: the limiter is the DRAM-level access pattern (every version
// read X as many 4KB-strided row-streams in 16-256B granules; m13's
// 6.3 TB/s ceiling is a single sequential stream per wave). Fix: a block's
// 16-row X-tile is 64KB CONTIGUOUS -- stage it pass-per-row (each wave
// instruction reads 1KB contiguous; the block walks 64KB linearly),
// converting fp32->bf16 into a 32KB swizzled LDS tile. Compute = v7's
// K-split x4 (4 waves, same 16 rows, K-quarter each), A-frags via
// ds_read_b128 with matching XOR swizzle (unit pu = u ^ (row&7), 2-way
// conflicts = free). Cross-wave reduce aliases the staging LDS after a
// barrier. grid (1024,3); 4-5 blocks/CU resident.
// ---------------------------------------------------------------------------
__global__ __launch_bounds__(256, 4) void proj_kernel(
    const float* __restrict__ k, const float* __restrict__ q,
    const float* __restrict__ v,
    const unsigned short* __restrict__ WL,
    unsigned short* __restrict__ ws)
{
    const int which = blockIdx.y;
    const float* X = (which == 0) ? k : (which == 1) ? q : v;
    const unsigned short* WLm = WL + (size_t)which * WLS;
    unsigned short* O = ws + (size_t)which * BTHb;

    __shared__ __align__(16) float smem[8192];          // 32 KB
    unsigned short* Xbf = (unsigned short*)smem;        // [16][1024] swizzled

    const int tid  = threadIdx.x;
    const int wave = __builtin_amdgcn_readfirstlane(tid >> 6);  // K-quarter
    const int lane = tid & 63;
    const int m    = lane & 15;
    const int quad = lane >> 4;
    const int row0 = blockIdx.x * 16;

    // ---- stage 16 rows x 1024 cols, SEQUENTIALLY: pass p reads row p ----
    // (wave instruction = 1KB contiguous; block walks its 64KB tile linearly)
    const float* Xt = X + (size_t)row0 * Cn + tid * 4;
#pragma unroll
    for (int p = 0; p < 16; ++p) {
        const float4 xv = *(const float4*)(Xt + (size_t)p * Cn);
        ushort4 xb;
        xb.x = hwbf16(xv.x); xb.y = hwbf16(xv.y);
        xb.z = hwbf16(xv.z); xb.w = hwbf16(xv.w);
        const int pu = (tid >> 1) ^ (p & 7);   // 16B-unit XOR swizzle
        *(ushort4*)&Xbf[p * 1024 + pu * 8 + (tid & 1) * 4] = xb;
    }
    __syncthreads();

    // ---- K-split x4 MFMA: wave owns 8 chunks of 32 ----
    f32x4 acc[4];
#pragma unroll
    for (int t = 0; t < 4; ++t) acc[t] = (f32x4){0.f, 0.f, 0.f, 0.f};

#pragma unroll
    for (int cc = 0; cc < 8; ++cc) {
        const int c  = wave * 8 + cc;
        const int pu = (c * 4 + quad) ^ (m & 7);
        const bf16x8 a = *(const bf16x8*)&Xbf[m * 1024 + pu * 8];
#pragma unroll
        for (int ht = 0; ht < 4; ++ht) {
            const bf16x8 bfr =
                *(const bf16x8*)&WLm[(size_t)((c * 4 + ht) * 64 + lane) * 8];
            acc[ht] = __builtin_amdgcn_mfma_f32_16x16x32_bf16(
                a, bfr, acc[ht], 0, 0, 0);
        }
    }

    // ---- cross-wave K-reduction; scratch aliases the staging LDS ----
    __syncthreads();   // everyone done reading Xbf
    float (*Rs)[64][17] = (float (*)[64][17])smem;      // 13 KB < 32 KB
    if (wave > 0) {
#pragma unroll
        for (int ht = 0; ht < 4; ++ht)
#pragma unroll
            for (int r = 0; r < 4; ++r)
                Rs[wave - 1][lane][ht * 4 + r] = acc[ht][r];
    }
    __syncthreads();
    if (wave == 0) {
#pragma unroll
        for (int w = 0; w < 3; ++w)
#pragma unroll
            for (int ht = 0; ht < 4; ++ht)
#pragma unroll
                for (int r = 0; r < 4; ++r)
                    acc[ht][r] += Rs[w][lane][ht * 4 + r];

        // D layout: col=lane&15, row=quad*4+reg
#pragma unroll
        for (int ht = 0; ht < 4; ++ht)
#pragma unroll
            for (int r = 0; r < 4; ++r)
                O[(size_t)(row0 + quad * 4 + r) * Hn + ht * 16 + m] =
                    bf16rne(acc[ht][r]);
    }
}

// ---------------------------------------------------------------------------
// MFMA flash attention. grid (32, 8); block 256 = 4 waves. (unchanged)
// ---------------------------------------------------------------------------
__global__ __launch_bounds__(256) void attn_kernel(
    const unsigned short* __restrict__ ws,
    const int* __restrict__ mask,
    float* __restrict__ out)
{
    const unsigned short* kh = ws;
    const unsigned short* qh = ws + BTHb;
    const unsigned short* vh = ws + 2 * BTHb;

    const int b   = blockIdx.y;
    const int qt  = blockIdx.x;
    const int tid = threadIdx.x;
    const int wave = __builtin_amdgcn_readfirstlane(tid >> 6);
    const int lane = tid & 63;
    const int ln   = lane & 15;
    const int quad = lane >> 4;

    __shared__ unsigned short Ks[64][72];   // [kpos][dim]
    __shared__ unsigned short Vt[64][72];   // [dim][kpos]
    __shared__ unsigned short Ps[64][72];   // [q-row local][kpos]
    __shared__ int Msk[64];

    const int wrb = qt * 64 + wave * 16;    // wave's first q-row

    // Q A-frags: A[m=ln][k=quad*8+j], 2 chunks of K=32
    bf16x8 qa[2];
#pragma unroll
    for (int kc = 0; kc < 2; ++kc)
        qa[kc] = *(const bf16x8*)(qh + ((size_t)b * Tn + wrb + ln) * Hn
                                     + kc * 32 + quad * 8);

    f32x4 oacc[4];
#pragma unroll
    for (int t = 0; t < 4; ++t) oacc[t] = (f32x4){0.f, 0.f, 0.f, 0.f};
    float mrow[4] = {-1e30f, -1e30f, -1e30f, -1e30f};
    float lrow[4] = {0.f, 0.f, 0.f, 0.f};

    // staging: K by (row=tid>>2, seg=tid&3)  [coalesced global, b128 LDS]
    //          V by (col=tid&63, seg=tid>>6) [conflict-free transpose writes]
    const int krow = tid >> 2, kseg = tid & 3;
    const int vcol = tid & 63, vseg = tid >> 6;

    uint4 kreg[2], vreg[2];
    int mreg = 0;
    {
        const unsigned short* kp =
            kh + ((size_t)b * Tn + krow) * Hn + kseg * 16;
        kreg[0] = *(const uint4*)kp;
        kreg[1] = *(const uint4*)(kp + 8);
        const unsigned short* vp =
            vh + ((size_t)b * Tn + vcol) * Hn + vseg * 16;
        vreg[0] = *(const uint4*)vp;
        vreg[1] = *(const uint4*)(vp + 8);
        if (tid < 64) mreg = mask[(size_t)b * Tn + tid];
    }

    for (int j = 0; j <= qt; ++j) {
        __syncthreads();   // previous tile's LDS readers done
        *(uint4*)&Ks[krow][kseg * 16]     = kreg[0];
        *(uint4*)&Ks[krow][kseg * 16 + 8] = kreg[1];
        {
            const unsigned short* vs = (const unsigned short*)vreg;
#pragma unroll
            for (int jj = 0; jj < 16; ++jj)
                Vt[vseg * 16 + jj][vcol] = vs[jj];
        }
        if (tid < 64) Msk[tid] = mreg;
        __syncthreads();   // staged tile visible

        if (j < qt) {      // prefetch next tile; latency overlaps compute
            const unsigned short* kp =
                kh + ((size_t)b * Tn + (j + 1) * 64 + krow) * Hn + kseg * 16;
            kreg[0] = *(const uint4*)kp;
            kreg[1] = *(const uint4*)(kp + 8);
            const unsigned short* vp =
                vh + ((size_t)b * Tn + (j + 1) * 64 + vcol) * Hn + vseg * 16;
            vreg[0] = *(const uint4*)vp;
            vreg[1] = *(const uint4*)(vp + 8);
            if (tid < 64) mreg = mask[(size_t)b * Tn + (j + 1) * 64 + tid];
        }

        // ---- S = Q K^T : 4 col-tiles (16 kpos each) x 2 K-chunks ----
        f32x4 sacc[4];
#pragma unroll
        for (int t = 0; t < 4; ++t) sacc[t] = (f32x4){0.f, 0.f, 0.f, 0.f};
#pragma unroll
        for (int kc = 0; kc < 2; ++kc) {
#pragma unroll
            for (int nt = 0; nt < 4; ++nt) {
                const bf16x8 kb =
                    *(const bf16x8*)&Ks[nt * 16 + ln][kc * 32 + quad * 8];
                sacc[nt] = __builtin_amdgcn_mfma_f32_16x16x32_bf16(
                    qa[kc], kb, sacc[nt], 0, 0, 0);
            }
        }

        // ---- online softmax in C-layout (rows quad*4+r, col nt*16+ln) ----
        const bool fullv = (j < qt);   // tile fully causal-valid for block
        float pv[4][4];
        float mt[4] = {-1e30f, -1e30f, -1e30f, -1e30f};
#pragma unroll
        for (int nt = 0; nt < 4; ++nt) {
            const bool mk = (Msk[nt * 16 + ln] != 0);
            const int kpos = j * 64 + nt * 16 + ln;
#pragma unroll
            for (int r = 0; r < 4; ++r) {
                float s = sacc[nt][r] * 0.125f;
                const bool valid =
                    mk && (fullv || kpos <= wrb + quad * 4 + r);
                s = valid ? s : -1e30f;
                pv[nt][r] = s;
                mt[r] = fmaxf(mt[r], s);
            }
        }
#pragma unroll
        for (int r = 0; r < 4; ++r) {
            mt[r] = fmaxf(mt[r], __shfl_xor(mt[r], 1));
            mt[r] = fmaxf(mt[r], __shfl_xor(mt[r], 2));
            mt[r] = fmaxf(mt[r], __shfl_xor(mt[r], 4));
            mt[r] = fmaxf(mt[r], __shfl_xor(mt[r], 8));
        }
        float alpha[4], rsum[4];
#pragma unroll
        for (int r = 0; r < 4; ++r) {
            const float mn = fmaxf(mrow[r], mt[r]);
            alpha[r] = __expf(mrow[r] - mn);
            mrow[r] = mn;
            rsum[r] = 0.f;
        }
#pragma unroll
        for (int nt = 0; nt < 4; ++nt)
#pragma unroll
            for (int r = 0; r < 4; ++r) {
                const float p = (pv[nt][r] <= -1e29f)
                                    ? 0.f
                                    : __expf(pv[nt][r] - mrow[r]);
                pv[nt][r] = p;
                rsum[r] += p;
            }
#pragma unroll
        for (int r = 0; r < 4; ++r) {
            rsum[r] += __shfl_xor(rsum[r], 1);
            rsum[r] += __shfl_xor(rsum[r], 2);
            rsum[r] += __shfl_xor(rsum[r], 4);
            rsum[r] += __shfl_xor(rsum[r], 8);
            lrow[r] = lrow[r] * alpha[r] + rsum[r];
        }
#pragma unroll
        for (int nt = 0; nt < 4; ++nt)
#pragma unroll
            for (int r = 0; r < 4; ++r) oacc[nt][r] *= alpha[r];

        // ---- P -> LDS (bf16), wave-private region ----
#pragma unroll
        for (int nt = 0; nt < 4; ++nt)
#pragma unroll
            for (int r = 0; r < 4; ++r)
                Ps[wave * 16 + quad * 4 + r][nt * 16 + ln] =
                    bf16rne(pv[nt][r]);
        // wave-private LDS round-trip: drain DS writes, keep vmcnt in flight
        asm volatile("s_waitcnt lgkmcnt(0)" ::: "memory");

        // ---- O += P V : A=P[m=ln][k], B=V^T[n=dim][k] ----
#pragma unroll
        for (int kc = 0; kc < 2; ++kc) {
            const bf16x8 pa =
                *(const bf16x8*)&Ps[wave * 16 + ln][kc * 32 + quad * 8];
#pragma unroll
            for (int nt = 0; nt < 4; ++nt) {
                const bf16x8 vb =
                    *(const bf16x8*)&Vt[nt * 16 + ln][kc * 32 + quad * 8];
                oacc[nt] = __builtin_amdgcn_mfma_f32_16x16x32_bf16(
                    pa, vb, oacc[nt], 0, 0, 0);
            }
        }
    }

    // ---- epilogue: divide by l, fp32 store ----
#pragma unroll
    for (int r = 0; r < 4; ++r) {
        const float inv = 1.0f / lrow[r];
        const size_t rowoff = ((size_t)b * Tn + wrb + quad * 4 + r) * Hn;
#pragma unroll
        for (int nt = 0; nt < 4; ++nt)
            out[rowoff + nt * 16 + ln] = oacc[nt][r] * inv;
    }
}

extern "C" void kernel_launch(void* const* d_in, const int* in_sizes, int n_in,
                              void* d_out, int out_size, void* d_ws, size_t ws_size,
                              hipStream_t stream)
{
    const float* k    = (const float*)d_in[0];
    const float* q    = (const float*)d_in[1];
    const float* v    = (const float*)d_in[2];
    const int*   mask = (const int*)d_in[3];
    const float* Wk   = (const float*)d_in[4];
    const float* Wq   = (const float*)d_in[5];
    const float* Wv   = (const float*)d_in[6];
    float* out = (float*)d_out;
    unsigned short* ws = (unsigned short*)d_ws;  // kh|qh|vh bf16, 6.3 MB

    // WL scratch lives in d_out (384 KB of 4 MB); attn fully overwrites out.
    unsigned short* WL = (unsigned short*)d_out;

    dim3 wb(256), wg(8, 3);
    wconv_kernel<<<wg, wb, 0, stream>>>(Wk, Wq, Wv, WL);

    dim3 pb(256), pg(Bn * Tn / 16, 3);
    proj_kernel<<<pg, pb, 0, stream>>>(k, q, v, WL, ws);

    dim3 ab(256), ag(Tn / 64, Bn);
    attn_kernel<<<ag, ab, 0, stream>>>(ws, mask, out);
}